// Round 9
// baseline (254.103 us; speedup 1.0000x reference)
//
#include <hip/hip_runtime.h>

// ---------------- problem constants ----------------
constexpr int B_  = 4;
constexpr int S_  = 2048;
constexpr int D_  = 1024;
constexpr int H_  = 16;
constexpr int DK_ = 64;
constexpr int M_  = B_ * S_;          // 8192 token rows

typedef __attribute__((ext_vector_type(8))) short short8;
typedef __attribute__((ext_vector_type(4))) float f32x4;
typedef __attribute__((ext_vector_type(4))) unsigned short us4;

union U8 { short8 s8; uint2 p[2]; unsigned int u[4]; };

__device__ __forceinline__ unsigned short f2b(float f) {
  unsigned int u = __float_as_uint(f);
  u += 0x7FFFu + ((u >> 16) & 1u);          // RNE
  return (unsigned short)(u >> 16);
}
__device__ __forceinline__ float b2f(unsigned short h) {
  return __uint_as_float(((unsigned int)h) << 16);
}
// packed f32x2 -> bf16x2 (RNE), single HW instr; low16 = src0
__device__ __forceinline__ unsigned int cvtpk(float lo, float hi) {
  unsigned int w;
  asm("v_cvt_pk_bf16_f32 %0, %1, %2" : "=v"(w) : "v"(lo), "v"(hi));
  return w;
}
// D = 2^S0
__device__ __forceinline__ float exp2v(float x) {
  float r;
  asm("v_exp_f32 %0, %1" : "=v"(r) : "v"(x));
  return r;
}

// async global->LDS, 16B per lane; LDS dest must be wave-uniform base (+ lane*16 by HW)
#define GLOAD16(g, l) __builtin_amdgcn_global_load_lds( \
    (const __attribute__((address_space(1))) unsigned int*)(g), \
    (__attribute__((address_space(3))) unsigned int*)(l), 16, 0, 0)

// ---------------- kernel 0: fp32 -> bf16 conversion (x, Wq|Wk|Wv) ----------------
__global__ __launch_bounds__(256) void conv_kernel(
    const float* __restrict__ x,
    const float* __restrict__ wq, const float* __restrict__ wk, const float* __restrict__ wv,
    unsigned short* __restrict__ xb, unsigned short* __restrict__ wb)
{
  const int NX4 = (M_ * D_) / 4;
  const int NW4 = (3 * D_ * D_) / 4;
  int stride = gridDim.x * blockDim.x;
  for (int i = blockIdx.x * blockDim.x + threadIdx.x; i < NX4 + NW4; i += stride) {
    const float4* src; unsigned short* dst; int o;
    if (i < NX4) { src = (const float4*)x; dst = xb; o = i; }
    else {
      int wi = i - NX4;
      int mat = wi >> 18;
      o = wi & 262143;
      src = (const float4*)(mat == 0 ? wq : (mat == 1 ? wk : wv));
      dst = wb + mat * (D_ * D_);
    }
    float4 v = src[o];
    us4 r; r.x = f2b(v.x); r.y = f2b(v.y); r.z = f2b(v.z); r.w = f2b(v.w);
    *(us4*)(dst + o * 4) = r;
  }
}

// ---------------- kernel 0b: Wo fp32 -> bf16 ----------------
__global__ __launch_bounds__(256) void conv_wo_kernel(
    const float* __restrict__ wo, unsigned short* __restrict__ wob)
{
  int i = blockIdx.x * 256 + threadIdx.x;       // 262144 float4s
  float4 v = ((const float4*)wo)[i];
  us4 r; r.x = f2b(v.x); r.y = f2b(v.y); r.z = f2b(v.z); r.w = f2b(v.w);
  *(us4*)(wob + i * 4) = r;
}

// ---------------- kernel 1: QKV projection GEMM (C = A * B^T) + fused RoPE -------------
__global__ __launch_bounds__(256, 2) void gemm_qkv_kernel(
    const unsigned short* __restrict__ xb,
    const unsigned short* __restrict__ wb,
    const float* __restrict__ cs,        // [2048][32][2] cos/sin
    const int* __restrict__ pos,
    unsigned short* __restrict__ qb,
    unsigned short* __restrict__ kb,
    unsigned short* __restrict__ vtb)
{
  __shared__ unsigned short As[2][128 * 64];   // 32 KB
  __shared__ unsigned short Bs[2][128 * 64];   // 32 KB
  const int tid  = threadIdx.x;
  const int lane = tid & 63;
  const int wid  = tid >> 6;
  const int wm = wid >> 1, wn = wid & 1;
  const int m0 = blockIdx.x * 128;
  const int n0 = blockIdx.y * 128;          // 0..3071
  const int l15 = lane & 15, l4 = lane >> 4;
  const int swz7 = l15 & 7;                 // frag-read swizzle (row&7 == l15&7)

  int srow[4], sgcc[4], slds[4];
  #pragma unroll
  for (int j = 0; j < 4; ++j) {
    int c = tid + j * 256;                  // chunk id 0..1023
    srow[j] = c >> 3;                       // row 0..127
    int cc  = c & 7;
    sgcc[j] = cc ^ (srow[j] & 7);           // inverse-swizzled global col-chunk
    slds[j] = (wid * 64 + j * 256) * 8;     // wave-uniform LDS base (shorts)
  }

  f32x4 acc[4][4] = {};

  #pragma unroll
  for (int j = 0; j < 4; ++j) {
    GLOAD16(xb + (m0 + srow[j]) * D_ + sgcc[j] * 8, &As[0][slds[j]]);
    GLOAD16(wb + (n0 + srow[j]) * D_ + sgcc[j] * 8, &Bs[0][slds[j]]);
  }
  __syncthreads();

  for (int t = 0; t < 16; ++t) {
    const int cur = t & 1, nxt = cur ^ 1;
    if (t < 15) {                           // stage-early: issue next tile under compute
      const int kcol = (t + 1) * 64;
      #pragma unroll
      for (int j = 0; j < 4; ++j) {
        GLOAD16(xb + (m0 + srow[j]) * D_ + kcol + sgcc[j] * 8, &As[nxt][slds[j]]);
        GLOAD16(wb + (n0 + srow[j]) * D_ + kcol + sgcc[j] * 8, &Bs[nxt][slds[j]]);
      }
    }
    const unsigned short* Ab = &As[cur][0];
    const unsigned short* Bb = &Bs[cur][0];
    #pragma unroll
    for (int ks = 0; ks < 2; ++ks) {
      const int cc = (ks * 4 + l4) ^ swz7;  // swizzled chunk within row
      short8 af[4], bfr[4];
      #pragma unroll
      for (int mi = 0; mi < 4; ++mi) af[mi]  = *(const short8*)&Ab[(wm*64 + mi*16 + l15)*64 + cc*8];
      #pragma unroll
      for (int ni = 0; ni < 4; ++ni) bfr[ni] = *(const short8*)&Bb[(wn*64 + ni*16 + l15)*64 + cc*8];
      __builtin_amdgcn_s_setprio(1);
      #pragma unroll
      for (int mi = 0; mi < 4; ++mi)
        #pragma unroll
        for (int ni = 0; ni < 4; ++ni)
          acc[mi][ni] = __builtin_amdgcn_mfma_f32_16x16x32_bf16(af[mi], bfr[ni], acc[mi][ni], 0, 0, 0);
      __builtin_amdgcn_s_setprio(0);
    }
    __syncthreads();                        // drains vmcnt (next tile landed) + joins
  }

  const int bidx = m0 >> 11;
  const int sbase = (m0 & 2047) + wm * 64;

  if (n0 < 2048) {
    // ---- q or k block: fused RoPE, [b][h][s][d] scatter ----
    unsigned short* dst = (n0 < 1024) ? qb : kb;
    const int nn0 = n0 & 1023;
    const float2* cs2 = (const float2*)cs;
    const float sg = (l15 & 1) ? 1.0f : -1.0f;
    #pragma unroll
    for (int mi = 0; mi < 4; ++mi)
      #pragma unroll
      for (int j = 0; j < 4; ++j) {
        int s = sbase + mi*16 + l4*4 + j;
        int p = pos[s];
        #pragma unroll
        for (int ni = 0; ni < 4; ++ni) {
          int col = nn0 + wn*64 + ni*16 + l15;
          int h = col >> 6, dd = col & 63;
          float val = acc[mi][ni][j];
          float par = __shfl_xor(val, 1);
          float2 cv = cs2[p*32 + (dd >> 1)];
          float r = fmaf(cv.x, val, sg * cv.y * par);
          dst[((bidx*H_ + h)*S_ + s)*DK_ + dd] = f2b(r);
        }
      }
  } else {
    // ---- v block: transposed scatter [b][h][d][s]; 8B packed stores ----
    const int nn0 = n0 & 1023;
    const int hB = (nn0 + wn*64) >> 6;
    #pragma unroll
    for (int mi = 0; mi < 4; ++mi) {
      int s4 = sbase + mi*16 + l4*4;
      #pragma unroll
      for (int ni = 0; ni < 4; ++ni) {
        int dd = ni*16 + l15;
        uint2 w;
        w.x = cvtpk(acc[mi][ni][0], acc[mi][ni][1]);
        w.y = cvtpk(acc[mi][ni][2], acc[mi][ni][3]);
        *(uint2*)(vtb + ((bidx*H_ + hB)*DK_ + dd)*S_ + s4) = w;
      }
    }
  }
}

// ---------------- kernel 3: causal flash attention v7 ----------------
// v6 + in-register P: MFMA K-slots are a reduction, so feed pa = cvtpk(sc) in the
// lane-natural key order key(l4,i) = (i>>2)*16 + l4*4 + (i&3) and read V with the SAME
// permuted order (2x ds_read_b64 per fragment). Kills Ps LDS + lgkmcnt(0) drain + the
// y0<->y1 serialization. Tree max/sum (chain depth 15 -> 4). LDS 32KB -> 5 blocks/CU.
__global__ __launch_bounds__(256, 5) void attn_kernel(
    const unsigned short* __restrict__ qb,
    const unsigned short* __restrict__ kb,
    const unsigned short* __restrict__ vtb,
    unsigned short* __restrict__ ao)
{
  __shared__ unsigned short Ks[2][64 * 64];    // [key][dim] linear, chunk-swizzled
  __shared__ unsigned short Vs[2][64 * 64];    // [dim][key] linear, chunk-swizzled
  const int tid = threadIdx.x, lane = tid & 63, wid = tid >> 6;
  const int l15 = lane & 15, l4 = lane >> 4;
  const int swz7 = l15 & 7;

  const int id  = blockIdx.x;                  // 0..1023
  const int xcd = id & 7, rem = id >> 3;       // rem: 0..127
  const int bh  = xcd * 8 + (rem & 7);         // 8 consecutive heads per XCD
  const int qt  = 15 - (rem >> 3);             // heavy q-tiles dispatched first
  const int q0  = qt * 128;
  const int nkt = 2 * qt + 2;

  const unsigned short* qp = qb  + bh * S_ * DK_;
  const unsigned short* kp = kb  + bh * S_ * DK_;
  const unsigned short* vp = vtb + bh * DK_ * S_;
  const int bidx = bh >> 4, h = bh & 15;

  // staging geometry: 512 chunks of 16B per matrix per tile; 2 chunks/thread
  int srow[2], sgcc[2], slds[2];
  #pragma unroll
  for (int j = 0; j < 2; ++j) {
    int c = tid + j * 256;                     // chunk id 0..511
    srow[j] = c >> 3;                          // row 0..63 (K: key, V: dim)
    int cc  = c & 7;
    sgcc[j] = cc ^ (srow[j] & 7);              // inverse-swizzled global col-chunk
    slds[j] = (wid * 64 + j * 256) * 8;        // wave-uniform LDS base (shorts)
  }

  // Q B-frags, two 16-row groups per wave, pre-scaled by (1/8)*log2(e)
  const float QSC = 0.18033688f;
  short8 qf[2][2];
  #pragma unroll
  for (int y = 0; y < 2; ++y)
    #pragma unroll
    for (int kbk = 0; kbk < 2; ++kbk) {
      short8 raw = *(const short8*)(qp + (q0 + y*64 + wid*16 + l15)*DK_ + kbk*32 + l4*8);
      #pragma unroll
      for (int i = 0; i < 8; ++i) {
        float f = b2f((unsigned short)raw[i]) * QSC;
        raw[i] = (short)f2b(f);
      }
      qf[y][kbk] = raw;
    }

  f32x4 oacc[2][4] = {};
  float mrun[2] = {-1e30f, -1e30f}, lrun[2] = {0.0f, 0.0f};

  // prologue: stage tile 0 -> buf 0
  #pragma unroll
  for (int j = 0; j < 2; ++j) {
    GLOAD16(kp + srow[j]*DK_ + sgcc[j]*8, &Ks[0][slds[j]]);
    GLOAD16(vp + srow[j]*S_  + sgcc[j]*8, &Vs[0][slds[j]]);
  }
  __syncthreads();                             // vmcnt drained: tile 0 visible

  // per-lane V b64 half-offset (shorts) and the 4 key-group chunk bases
  const int vhalf = (l4 & 1) * 4;
  const int g0 = l4 >> 1;                      // keys  0..15 -> chunks 0,1
  for (int kt = 0; kt < nkt; ++kt) {
    const int cur = kt & 1, nxt = cur ^ 1;
    if (kt + 1 < nkt) {                        // stage-early: next tile under compute
      const int kb0 = (kt + 1) * 64;
      #pragma unroll
      for (int j = 0; j < 2; ++j) {
        GLOAD16(kp + (kb0 + srow[j])*DK_ + sgcc[j]*8, &Ks[nxt][slds[j]]);
        GLOAD16(vp + srow[j]*S_ + kb0   + sgcc[j]*8, &Vs[nxt][slds[j]]);
      }
    }

    #pragma unroll
    for (int y = 0; y < 2; ++y) {
      if (kt > 2*qt + y) continue;             // fully masked group

      // swapped QK^T: lane owns q-row (l15), 16 keys in-register
      f32x4 sc[4];
      __builtin_amdgcn_s_setprio(1);
      #pragma unroll
      for (int nb = 0; nb < 4; ++nb) {
        const int rb = (nb*16 + l15) * 64;
        short8 k0 = *(const short8*)&Ks[cur][rb + ((l4     ^ swz7) * 8)];
        short8 k1 = *(const short8*)&Ks[cur][rb + (((4+l4) ^ swz7) * 8)];
        f32x4 z = {};
        z = __builtin_amdgcn_mfma_f32_16x16x32_bf16(k0, qf[y][0], z, 0, 0, 0);
        z = __builtin_amdgcn_mfma_f32_16x16x32_bf16(k1, qf[y][1], z, 0, 0, 0);
        sc[nb] = z;
      }
      __builtin_amdgcn_s_setprio(0);

      if (kt == 2*qt + y) {                    // diagonal tile mask
        const int qg = q0 + y*64 + wid*16 + l15;
        #pragma unroll
        for (int nb = 0; nb < 4; ++nb)
          #pragma unroll
          for (int j = 0; j < 4; ++j) {
            int kg = kt*64 + nb*16 + l4*4 + j;
            if (kg > qg) sc[nb][j] = -1e30f;
          }
      }

      // online softmax in log2 domain, defer-max THR=8; TREE reductions (depth 4)
      float mq[4];
      #pragma unroll
      for (int nb = 0; nb < 4; ++nb)
        mq[nb] = fmaxf(fmaxf(sc[nb][0], sc[nb][1]), fmaxf(sc[nb][2], sc[nb][3]));
      float tm = fmaxf(fmaxf(mq[0], mq[1]), fmaxf(mq[2], mq[3]));
      tm = fmaxf(tm, __shfl_xor(tm, 16));
      tm = fmaxf(tm, __shfl_xor(tm, 32));
      if (!__all(tm - mrun[y] <= 8.0f)) {
        float mnew = fmaxf(mrun[y], tm);
        float corr = exp2v(mrun[y] - mnew);
        mrun[y] = mnew;
        lrun[y] *= corr;
        #pragma unroll
        for (int j = 0; j < 4; ++j) {
          float cj = __shfl(corr, l4*4 + j);
          #pragma unroll
          for (int nb = 0; nb < 4; ++nb) oacc[y][nb][j] *= cj;
        }
      }
      float sq[4];
      #pragma unroll
      for (int nb = 0; nb < 4; ++nb) {
        #pragma unroll
        for (int j = 0; j < 4; ++j) sc[nb][j] = exp2v(sc[nb][j] - mrun[y]);
        sq[nb] = (sc[nb][0] + sc[nb][1]) + (sc[nb][2] + sc[nb][3]);
      }
      float rs = (sq[0] + sq[1]) + (sq[2] + sq[3]);
      rs += __shfl_xor(rs, 16);
      rs += __shfl_xor(rs, 32);
      lrun[y] += rs;

      // P -> A-frags IN-REGISTER (permuted key order; V read with same order)
      U8 pa0, pa1;
      pa0.u[0] = cvtpk(sc[0][0], sc[0][1]); pa0.u[1] = cvtpk(sc[0][2], sc[0][3]);
      pa0.u[2] = cvtpk(sc[1][0], sc[1][1]); pa0.u[3] = cvtpk(sc[1][2], sc[1][3]);
      pa1.u[0] = cvtpk(sc[2][0], sc[2][1]); pa1.u[1] = cvtpk(sc[2][2], sc[2][3]);
      pa1.u[2] = cvtpk(sc[3][0], sc[3][1]); pa1.u[3] = cvtpk(sc[3][2], sc[3][3]);

      // O += P * V  (V b64 reads at permuted key groups, chunk-swizzled)
      __builtin_amdgcn_s_setprio(1);
      #pragma unroll
      for (int nb = 0; nb < 4; ++nb) {
        const int rb = (nb*16 + l15) * 64;
        U8 v0, v1;
        v0.p[0] = *(const uint2*)&Vs[cur][rb + (( g0      ^ swz7) * 8) + vhalf];
        v0.p[1] = *(const uint2*)&Vs[cur][rb + (((2 + g0) ^ swz7) * 8) + vhalf];
        v1.p[0] = *(const uint2*)&Vs[cur][rb + (((4 + g0) ^ swz7) * 8) + vhalf];
        v1.p[1] = *(const uint2*)&Vs[cur][rb + (((6 + g0) ^ swz7) * 8) + vhalf];
        oacc[y][nb] = __builtin_amdgcn_mfma_f32_16x16x32_bf16(pa0.s8, v0.s8, oacc[y][nb], 0, 0, 0);
        oacc[y][nb] = __builtin_amdgcn_mfma_f32_16x16x32_bf16(pa1.s8, v1.s8, oacc[y][nb], 0, 0, 0);
      }
      __builtin_amdgcn_s_setprio(0);
    }

    __syncthreads();                           // drains vmcnt (nxt staged) + joins
  }

  #pragma unroll
  for (int y = 0; y < 2; ++y)
    #pragma unroll
    for (int j = 0; j < 4; ++j) {
      float lj = __shfl(lrun[y], l4*4 + j);
      float inv = 1.0f / lj;
      int row = q0 + y*64 + wid*16 + l4*4 + j;
      #pragma unroll
      for (int nb = 0; nb < 4; ++nb) {
        int dim = nb*16 + l15;
        ao[((bidx*S_ + row)*H_ + h)*DK_ + dim] = f2b(oacc[y][nb][j] * inv);
      }
    }
}

// ---------------- kernel 4: output projection (C = A * Wo^T), fp32 out -----------------
__global__ __launch_bounds__(256, 2) void gemm_out_kernel(
    const unsigned short* __restrict__ ao,
    const unsigned short* __restrict__ wob,
    float* __restrict__ out)
{
  __shared__ unsigned short As[2][128 * 64];
  __shared__ unsigned short Bs[2][128 * 64];
  const int tid = threadIdx.x, lane = tid & 63, wid = tid >> 6;
  const int wm = wid >> 1, wn = wid & 1;
  const int m0 = blockIdx.x * 128, n0 = blockIdx.y * 128;
  const int l15 = lane & 15, l4 = lane >> 4;
  const int swz7 = l15 & 7;

  int srow[4], sgcc[4], slds[4];
  #pragma unroll
  for (int j = 0; j < 4; ++j) {
    int c = tid + j * 256;
    srow[j] = c >> 3;
    int cc  = c & 7;
    sgcc[j] = cc ^ (srow[j] & 7);
    slds[j] = (wid * 64 + j * 256) * 8;
  }

  f32x4 acc[4][4] = {};

  #pragma unroll
  for (int j = 0; j < 4; ++j) {
    GLOAD16(ao  + (m0 + srow[j]) * D_ + sgcc[j] * 8, &As[0][slds[j]]);
    GLOAD16(wob + (n0 + srow[j]) * D_ + sgcc[j] * 8, &Bs[0][slds[j]]);
  }
  __syncthreads();

  for (int t = 0; t < 16; ++t) {
    const int cur = t & 1, nxt = cur ^ 1;
    if (t < 15) {
      const int kcol = (t + 1) * 64;
      #pragma unroll
      for (int j = 0; j < 4; ++j) {
        GLOAD16(ao  + (m0 + srow[j]) * D_ + kcol + sgcc[j] * 8, &As[nxt][slds[j]]);
        GLOAD16(wob + (n0 + srow[j]) * D_ + kcol + sgcc[j] * 8, &Bs[nxt][slds[j]]);
      }
    }
    const unsigned short* Ab = &As[cur][0];
    const unsigned short* Bb = &Bs[cur][0];
    #pragma unroll
    for (int ks = 0; ks < 2; ++ks) {
      const int cc = (ks * 4 + l4) ^ swz7;
      short8 af[4], bfr[4];
      #pragma unroll
      for (int mi = 0; mi < 4; ++mi) af[mi]  = *(const short8*)&Ab[(wm*64 + mi*16 + l15)*64 + cc*8];
      #pragma unroll
      for (int ni = 0; ni < 4; ++ni) bfr[ni] = *(const short8*)&Bb[(wn*64 + ni*16 + l15)*64 + cc*8];
      __builtin_amdgcn_s_setprio(1);
      #pragma unroll
      for (int mi = 0; mi < 4; ++mi)
        #pragma unroll
        for (int ni = 0; ni < 4; ++ni)
          acc[mi][ni] = __builtin_amdgcn_mfma_f32_16x16x32_bf16(af[mi], bfr[ni], acc[mi][ni], 0, 0, 0);
      __builtin_amdgcn_s_setprio(0);
    }
    __syncthreads();
  }

  #pragma unroll
  for (int mi = 0; mi < 4; ++mi)
    #pragma unroll
    for (int ni = 0; ni < 4; ++ni)
      #pragma unroll
      for (int j = 0; j < 4; ++j) {
        int row = m0 + wm*64 + mi*16 + l4*4 + j;
        int col = n0 + wn*64 + ni*16 + l15;
        out[row * D_ + col] = acc[mi][ni][j];
      }
}

// ---------------- launcher ----------------
extern "C" void kernel_launch(void* const* d_in, const int* in_sizes, int n_in,
                              void* d_out, int out_size, void* d_ws, size_t ws_size,
                              hipStream_t stream)
{
  const float* x  = (const float*)d_in[0];
  const float* wq = (const float*)d_in[1];
  const float* wk = (const float*)d_in[2];
  const float* wv = (const float*)d_in[3];
  const float* wo = (const float*)d_in[4];
  const float* cs = (const float*)d_in[5];
  const int*  pos = (const int*)d_in[6];
  float* out = (float*)d_out;

  unsigned short* xb = (unsigned short*)d_out;   // d_out as scratch until final GEMM
  unsigned short* wb = xb + M_ * D_;

  unsigned short* qb  = (unsigned short*)d_ws;
  unsigned short* kbf = qb  + M_ * D_;
  unsigned short* vtb = kbf + M_ * D_;
  unsigned short* aob = vtb + M_ * D_;
  unsigned short* wob = qb;                      // dead q region after attn

  conv_kernel<<<dim3(2048), dim3(256), 0, stream>>>(x, wq, wk, wv, xb, wb);
  gemm_qkv_kernel<<<dim3(64, 24), dim3(256), 0, stream>>>(xb, wb, cs, pos, qb, kbf, vtb);
  attn_kernel<<<dim3(1024), dim3(256), 0, stream>>>(qb, kbf, vtb, aob);
  conv_wo_kernel<<<dim3(1024), dim3(256), 0, stream>>>(wo, wob);
  gemm_out_kernel<<<dim3(64, 8), dim3(256), 0, stream>>>(aob, wob, out);

  (void)in_sizes; (void)n_in; (void)out_size; (void)ws_size;
}

// Round 10
// 253.146 us; speedup vs baseline: 1.0038x; 1.0038x over previous
//
#include <hip/hip_runtime.h>

// ---------------- problem constants ----------------
constexpr int B_  = 4;
constexpr int S_  = 2048;
constexpr int D_  = 1024;
constexpr int H_  = 16;
constexpr int DK_ = 64;
constexpr int M_  = B_ * S_;          // 8192 token rows

typedef __attribute__((ext_vector_type(8))) short short8;
typedef __attribute__((ext_vector_type(4))) float f32x4;
typedef __attribute__((ext_vector_type(4))) unsigned short us4;
typedef __attribute__((ext_vector_type(4))) unsigned int u32x4;

__device__ __forceinline__ unsigned short f2b(float f) {
  unsigned int u = __float_as_uint(f);
  u += 0x7FFFu + ((u >> 16) & 1u);          // RNE
  return (unsigned short)(u >> 16);
}
__device__ __forceinline__ float b2f(unsigned short h) {
  return __uint_as_float(((unsigned int)h) << 16);
}
// packed f32x2 -> bf16x2 (RNE), single HW instr; low16 = src0
__device__ __forceinline__ unsigned int cvtpk(float lo, float hi) {
  unsigned int w;
  asm("v_cvt_pk_bf16_f32 %0, %1, %2" : "=v"(w) : "v"(lo), "v"(hi));
  return w;
}
// D = 2^S0
__device__ __forceinline__ float exp2v(float x) {
  float r;
  asm("v_exp_f32 %0, %1" : "=v"(r) : "v"(x));
  return r;
}

// async global->LDS, 16B per lane; LDS dest must be wave-uniform base (+ lane*16 by HW)
#define GLOAD16(g, l) __builtin_amdgcn_global_load_lds( \
    (const __attribute__((address_space(1))) unsigned int*)(g), \
    (__attribute__((address_space(3))) unsigned int*)(l), 16, 0, 0)

// ---------------- kernel 0: fp32 -> bf16 conversion (x, Wq|Wk|Wv) ----------------
__global__ __launch_bounds__(256) void conv_kernel(
    const float* __restrict__ x,
    const float* __restrict__ wq, const float* __restrict__ wk, const float* __restrict__ wv,
    unsigned short* __restrict__ xb, unsigned short* __restrict__ wb)
{
  const int NX4 = (M_ * D_) / 4;
  const int NW4 = (3 * D_ * D_) / 4;
  int stride = gridDim.x * blockDim.x;
  for (int i = blockIdx.x * blockDim.x + threadIdx.x; i < NX4 + NW4; i += stride) {
    const float4* src; unsigned short* dst; int o;
    if (i < NX4) { src = (const float4*)x; dst = xb; o = i; }
    else {
      int wi = i - NX4;
      int mat = wi >> 18;
      o = wi & 262143;
      src = (const float4*)(mat == 0 ? wq : (mat == 1 ? wk : wv));
      dst = wb + mat * (D_ * D_);
    }
    float4 v = src[o];
    us4 r; r.x = f2b(v.x); r.y = f2b(v.y); r.z = f2b(v.z); r.w = f2b(v.w);
    *(us4*)(dst + o * 4) = r;
  }
}

// ---------------- kernel 0b: Wo fp32 -> bf16 ----------------
__global__ __launch_bounds__(256) void conv_wo_kernel(
    const float* __restrict__ wo, unsigned short* __restrict__ wob)
{
  int i = blockIdx.x * 256 + threadIdx.x;       // 262144 float4s
  float4 v = ((const float4*)wo)[i];
  us4 r; r.x = f2b(v.x); r.y = f2b(v.y); r.z = f2b(v.z); r.w = f2b(v.w);
  *(us4*)(wob + i * 4) = r;
}

// ---------------- kernel 1: QKV projection GEMM (C = A * B^T) + fused RoPE -------------
__global__ __launch_bounds__(256, 2) void gemm_qkv_kernel(
    const unsigned short* __restrict__ xb,
    const unsigned short* __restrict__ wb,
    const float* __restrict__ cs,        // [2048][32][2] cos/sin
    const int* __restrict__ pos,
    unsigned short* __restrict__ qb,
    unsigned short* __restrict__ kb,
    unsigned short* __restrict__ vtb)
{
  __shared__ unsigned short As[2][128 * 64];   // 32 KB
  __shared__ unsigned short Bs[2][128 * 64];   // 32 KB
  const int tid  = threadIdx.x;
  const int lane = tid & 63;
  const int wid  = tid >> 6;
  const int wm = wid >> 1, wn = wid & 1;
  const int m0 = blockIdx.x * 128;
  const int n0 = blockIdx.y * 128;          // 0..3071
  const int l15 = lane & 15, l4 = lane >> 4;
  const int swz7 = l15 & 7;                 // frag-read swizzle (row&7 == l15&7)

  int srow[4], sgcc[4], slds[4];
  #pragma unroll
  for (int j = 0; j < 4; ++j) {
    int c = tid + j * 256;                  // chunk id 0..1023
    srow[j] = c >> 3;                       // row 0..127
    int cc  = c & 7;
    sgcc[j] = cc ^ (srow[j] & 7);           // inverse-swizzled global col-chunk
    slds[j] = (wid * 64 + j * 256) * 8;     // wave-uniform LDS base (shorts)
  }

  f32x4 acc[4][4] = {};

  #pragma unroll
  for (int j = 0; j < 4; ++j) {
    GLOAD16(xb + (m0 + srow[j]) * D_ + sgcc[j] * 8, &As[0][slds[j]]);
    GLOAD16(wb + (n0 + srow[j]) * D_ + sgcc[j] * 8, &Bs[0][slds[j]]);
  }
  __syncthreads();

  for (int t = 0; t < 16; ++t) {
    const int cur = t & 1, nxt = cur ^ 1;
    if (t < 15) {                           // stage-early: issue next tile under compute
      const int kcol = (t + 1) * 64;
      #pragma unroll
      for (int j = 0; j < 4; ++j) {
        GLOAD16(xb + (m0 + srow[j]) * D_ + kcol + sgcc[j] * 8, &As[nxt][slds[j]]);
        GLOAD16(wb + (n0 + srow[j]) * D_ + kcol + sgcc[j] * 8, &Bs[nxt][slds[j]]);
      }
    }
    const unsigned short* Ab = &As[cur][0];
    const unsigned short* Bb = &Bs[cur][0];
    #pragma unroll
    for (int ks = 0; ks < 2; ++ks) {
      const int cc = (ks * 4 + l4) ^ swz7;  // swizzled chunk within row
      short8 af[4], bfr[4];
      #pragma unroll
      for (int mi = 0; mi < 4; ++mi) af[mi]  = *(const short8*)&Ab[(wm*64 + mi*16 + l15)*64 + cc*8];
      #pragma unroll
      for (int ni = 0; ni < 4; ++ni) bfr[ni] = *(const short8*)&Bb[(wn*64 + ni*16 + l15)*64 + cc*8];
      __builtin_amdgcn_s_setprio(1);
      #pragma unroll
      for (int mi = 0; mi < 4; ++mi)
        #pragma unroll
        for (int ni = 0; ni < 4; ++ni)
          acc[mi][ni] = __builtin_amdgcn_mfma_f32_16x16x32_bf16(af[mi], bfr[ni], acc[mi][ni], 0, 0, 0);
      __builtin_amdgcn_s_setprio(0);
    }
    __syncthreads();                        // drains vmcnt (next tile landed) + joins
  }

  const int bidx = m0 >> 11;
  const int sbase = (m0 & 2047) + wm * 64;

  if (n0 < 2048) {
    // ---- q or k block: fused RoPE, [b][h][s][d] scatter ----
    unsigned short* dst = (n0 < 1024) ? qb : kb;
    const int nn0 = n0 & 1023;
    const float2* cs2 = (const float2*)cs;
    const float sg = (l15 & 1) ? 1.0f : -1.0f;
    #pragma unroll
    for (int mi = 0; mi < 4; ++mi)
      #pragma unroll
      for (int j = 0; j < 4; ++j) {
        int s = sbase + mi*16 + l4*4 + j;
        int p = pos[s];
        #pragma unroll
        for (int ni = 0; ni < 4; ++ni) {
          int col = nn0 + wn*64 + ni*16 + l15;
          int h = col >> 6, dd = col & 63;
          float val = acc[mi][ni][j];
          float par = __shfl_xor(val, 1);
          float2 cv = cs2[p*32 + (dd >> 1)];
          float r = fmaf(cv.x, val, sg * cv.y * par);
          dst[((bidx*H_ + h)*S_ + s)*DK_ + dd] = f2b(r);
        }
      }
  } else {
    // ---- v block: transposed scatter [b][h][d][s]; 8B packed stores ----
    const int nn0 = n0 & 1023;
    const int hB = (nn0 + wn*64) >> 6;
    #pragma unroll
    for (int mi = 0; mi < 4; ++mi) {
      int s4 = sbase + mi*16 + l4*4;
      #pragma unroll
      for (int ni = 0; ni < 4; ++ni) {
        int dd = ni*16 + l15;
        uint2 w;
        w.x = cvtpk(acc[mi][ni][0], acc[mi][ni][1]);
        w.y = cvtpk(acc[mi][ni][2], acc[mi][ni][3]);
        *(uint2*)(vtb + ((bidx*H_ + hB)*DK_ + dd)*S_ + s4) = w;
      }
    }
  }
}

// ---------------- kernel 3: causal flash attention v7b ----------------
// Round-9 structure (in-register P via permuted MFMA K-slots) with the scratch bug
// fixed: all fragment assembly via ext-vector literals + __builtin_bit_cast (register-
// resident), no unions. LDS 32KB -> 5 blocks/CU.
__global__ __launch_bounds__(256, 5) void attn_kernel(
    const unsigned short* __restrict__ qb,
    const unsigned short* __restrict__ kb,
    const unsigned short* __restrict__ vtb,
    unsigned short* __restrict__ ao)
{
  __shared__ unsigned short Ks[2][64 * 64];    // [key][dim] linear, chunk-swizzled
  __shared__ unsigned short Vs[2][64 * 64];    // [dim][key] linear, chunk-swizzled
  const int tid = threadIdx.x, lane = tid & 63, wid = tid >> 6;
  const int l15 = lane & 15, l4 = lane >> 4;
  const int swz7 = l15 & 7;

  const int id  = blockIdx.x;                  // 0..1023
  const int xcd = id & 7, rem = id >> 3;       // rem: 0..127
  const int bh  = xcd * 8 + (rem & 7);         // 8 consecutive heads per XCD
  const int qt  = 15 - (rem >> 3);             // heavy q-tiles dispatched first
  const int q0  = qt * 128;
  const int nkt = 2 * qt + 2;

  const unsigned short* qp = qb  + bh * S_ * DK_;
  const unsigned short* kp = kb  + bh * S_ * DK_;
  const unsigned short* vp = vtb + bh * DK_ * S_;
  const int bidx = bh >> 4, h = bh & 15;

  // staging geometry: 512 chunks of 16B per matrix per tile; 2 chunks/thread
  int srow[2], sgcc[2], slds[2];
  #pragma unroll
  for (int j = 0; j < 2; ++j) {
    int c = tid + j * 256;                     // chunk id 0..511
    srow[j] = c >> 3;                          // row 0..63 (K: key, V: dim)
    int cc  = c & 7;
    sgcc[j] = cc ^ (srow[j] & 7);              // inverse-swizzled global col-chunk
    slds[j] = (wid * 64 + j * 256) * 8;        // wave-uniform LDS base (shorts)
  }

  // Q B-frags, two 16-row groups per wave, pre-scaled by (1/8)*log2(e)
  const float QSC = 0.18033688f;
  short8 qf[2][2];
  #pragma unroll
  for (int y = 0; y < 2; ++y)
    #pragma unroll
    for (int kbk = 0; kbk < 2; ++kbk) {
      short8 raw = *(const short8*)(qp + (q0 + y*64 + wid*16 + l15)*DK_ + kbk*32 + l4*8);
      #pragma unroll
      for (int i = 0; i < 8; ++i) {
        float f = b2f((unsigned short)raw[i]) * QSC;
        raw[i] = (short)f2b(f);
      }
      qf[y][kbk] = raw;
    }

  f32x4 oacc[2][4] = {};
  float mrun[2] = {-1e30f, -1e30f}, lrun[2] = {0.0f, 0.0f};

  // prologue: stage tile 0 -> buf 0
  #pragma unroll
  for (int j = 0; j < 2; ++j) {
    GLOAD16(kp + srow[j]*DK_ + sgcc[j]*8, &Ks[0][slds[j]]);
    GLOAD16(vp + srow[j]*S_  + sgcc[j]*8, &Vs[0][slds[j]]);
  }
  __syncthreads();                             // vmcnt drained: tile 0 visible

  const int vhalf = (l4 & 1) * 4;              // b64 half within 16B chunk (shorts)
  const int g0 = l4 >> 1;                      // chunk of keys l4*4..l4*4+3
  for (int kt = 0; kt < nkt; ++kt) {
    const int cur = kt & 1, nxt = cur ^ 1;
    if (kt + 1 < nkt) {                        // stage-early: next tile under compute
      const int kb0 = (kt + 1) * 64;
      #pragma unroll
      for (int j = 0; j < 2; ++j) {
        GLOAD16(kp + (kb0 + srow[j])*DK_ + sgcc[j]*8, &Ks[nxt][slds[j]]);
        GLOAD16(vp + srow[j]*S_ + kb0   + sgcc[j]*8, &Vs[nxt][slds[j]]);
      }
    }

    #pragma unroll
    for (int y = 0; y < 2; ++y) {
      if (kt > 2*qt + y) continue;             // fully masked group

      // swapped QK^T: lane owns q-row (l15), 16 keys in-register
      f32x4 sc[4];
      __builtin_amdgcn_s_setprio(1);
      #pragma unroll
      for (int nb = 0; nb < 4; ++nb) {
        const int rb = (nb*16 + l15) * 64;
        short8 k0 = *(const short8*)&Ks[cur][rb + ((l4     ^ swz7) * 8)];
        short8 k1 = *(const short8*)&Ks[cur][rb + (((4+l4) ^ swz7) * 8)];
        f32x4 z = {};
        z = __builtin_amdgcn_mfma_f32_16x16x32_bf16(k0, qf[y][0], z, 0, 0, 0);
        z = __builtin_amdgcn_mfma_f32_16x16x32_bf16(k1, qf[y][1], z, 0, 0, 0);
        sc[nb] = z;
      }
      __builtin_amdgcn_s_setprio(0);

      if (kt == 2*qt + y) {                    // diagonal tile mask
        const int qg = q0 + y*64 + wid*16 + l15;
        #pragma unroll
        for (int nb = 0; nb < 4; ++nb)
          #pragma unroll
          for (int j = 0; j < 4; ++j) {
            int kg = kt*64 + nb*16 + l4*4 + j;
            if (kg > qg) sc[nb][j] = -1e30f;
          }
      }

      // online softmax in log2 domain, defer-max THR=8; tree reductions
      float mq[4];
      #pragma unroll
      for (int nb = 0; nb < 4; ++nb)
        mq[nb] = fmaxf(fmaxf(sc[nb][0], sc[nb][1]), fmaxf(sc[nb][2], sc[nb][3]));
      float tm = fmaxf(fmaxf(mq[0], mq[1]), fmaxf(mq[2], mq[3]));
      tm = fmaxf(tm, __shfl_xor(tm, 16));
      tm = fmaxf(tm, __shfl_xor(tm, 32));
      if (!__all(tm - mrun[y] <= 8.0f)) {
        float mnew = fmaxf(mrun[y], tm);
        float corr = exp2v(mrun[y] - mnew);
        mrun[y] = mnew;
        lrun[y] *= corr;
        #pragma unroll
        for (int j = 0; j < 4; ++j) {
          float cj = __shfl(corr, l4*4 + j);
          #pragma unroll
          for (int nb = 0; nb < 4; ++nb) oacc[y][nb][j] *= cj;
        }
      }
      float sq[4];
      #pragma unroll
      for (int nb = 0; nb < 4; ++nb) {
        #pragma unroll
        for (int j = 0; j < 4; ++j) sc[nb][j] = exp2v(sc[nb][j] - mrun[y]);
        sq[nb] = (sc[nb][0] + sc[nb][1]) + (sc[nb][2] + sc[nb][3]);
      }
      float rs = (sq[0] + sq[1]) + (sq[2] + sq[3]);
      rs += __shfl_xor(rs, 16);
      rs += __shfl_xor(rs, 32);
      lrun[y] += rs;

      // P -> A-frags IN-REGISTER via vector literals + bit_cast (no scratch)
      u32x4 pa0v = { cvtpk(sc[0][0], sc[0][1]), cvtpk(sc[0][2], sc[0][3]),
                     cvtpk(sc[1][0], sc[1][1]), cvtpk(sc[1][2], sc[1][3]) };
      u32x4 pa1v = { cvtpk(sc[2][0], sc[2][1]), cvtpk(sc[2][2], sc[2][3]),
                     cvtpk(sc[3][0], sc[3][1]), cvtpk(sc[3][2], sc[3][3]) };
      short8 pa0 = __builtin_bit_cast(short8, pa0v);
      short8 pa1 = __builtin_bit_cast(short8, pa1v);

      // O += P * V  (V b64 reads in the SAME permuted key order, chunk-swizzled)
      __builtin_amdgcn_s_setprio(1);
      #pragma unroll
      for (int nb = 0; nb < 4; ++nb) {
        const int rb = (nb*16 + l15) * 64;
        uint2 a0 = *(const uint2*)&Vs[cur][rb + (( g0      ^ swz7) * 8) + vhalf];
        uint2 a1 = *(const uint2*)&Vs[cur][rb + (((2 + g0) ^ swz7) * 8) + vhalf];
        uint2 b0 = *(const uint2*)&Vs[cur][rb + (((4 + g0) ^ swz7) * 8) + vhalf];
        uint2 b1 = *(const uint2*)&Vs[cur][rb + (((6 + g0) ^ swz7) * 8) + vhalf];
        u32x4 v0v = { a0.x, a0.y, a1.x, a1.y };
        u32x4 v1v = { b0.x, b0.y, b1.x, b1.y };
        short8 v0 = __builtin_bit_cast(short8, v0v);
        short8 v1 = __builtin_bit_cast(short8, v1v);
        oacc[y][nb] = __builtin_amdgcn_mfma_f32_16x16x32_bf16(pa0, v0, oacc[y][nb], 0, 0, 0);
        oacc[y][nb] = __builtin_amdgcn_mfma_f32_16x16x32_bf16(pa1, v1, oacc[y][nb], 0, 0, 0);
      }
      __builtin_amdgcn_s_setprio(0);
    }

    __syncthreads();                           // drains vmcnt (nxt staged) + joins
  }

  #pragma unroll
  for (int y = 0; y < 2; ++y)
    #pragma unroll
    for (int j = 0; j < 4; ++j) {
      float lj = __shfl(lrun[y], l4*4 + j);
      float inv = 1.0f / lj;
      int row = q0 + y*64 + wid*16 + l4*4 + j;
      #pragma unroll
      for (int nb = 0; nb < 4; ++nb) {
        int dim = nb*16 + l15;
        ao[((bidx*S_ + row)*H_ + h)*DK_ + dim] = f2b(oacc[y][nb][j] * inv);
      }
    }
}

// ---------------- kernel 4: output projection (C = A * Wo^T), fp32 out -----------------
__global__ __launch_bounds__(256, 2) void gemm_out_kernel(
    const unsigned short* __restrict__ ao,
    const unsigned short* __restrict__ wob,
    float* __restrict__ out)
{
  __shared__ unsigned short As[2][128 * 64];
  __shared__ unsigned short Bs[2][128 * 64];
  const int tid = threadIdx.x, lane = tid & 63, wid = tid >> 6;
  const int wm = wid >> 1, wn = wid & 1;
  const int m0 = blockIdx.x * 128, n0 = blockIdx.y * 128;
  const int l15 = lane & 15, l4 = lane >> 4;
  const int swz7 = l15 & 7;

  int srow[4], sgcc[4], slds[4];
  #pragma unroll
  for (int j = 0; j < 4; ++j) {
    int c = tid + j * 256;
    srow[j] = c >> 3;
    int cc  = c & 7;
    sgcc[j] = cc ^ (srow[j] & 7);
    slds[j] = (wid * 64 + j * 256) * 8;
  }

  f32x4 acc[4][4] = {};

  #pragma unroll
  for (int j = 0; j < 4; ++j) {
    GLOAD16(ao  + (m0 + srow[j]) * D_ + sgcc[j] * 8, &As[0][slds[j]]);
    GLOAD16(wob + (n0 + srow[j]) * D_ + sgcc[j] * 8, &Bs[0][slds[j]]);
  }
  __syncthreads();

  for (int t = 0; t < 16; ++t) {
    const int cur = t & 1, nxt = cur ^ 1;
    if (t < 15) {
      const int kcol = (t + 1) * 64;
      #pragma unroll
      for (int j = 0; j < 4; ++j) {
        GLOAD16(ao  + (m0 + srow[j]) * D_ + kcol + sgcc[j] * 8, &As[nxt][slds[j]]);
        GLOAD16(wob + (n0 + srow[j]) * D_ + kcol + sgcc[j] * 8, &Bs[nxt][slds[j]]);
      }
    }
    const unsigned short* Ab = &As[cur][0];
    const unsigned short* Bb = &Bs[cur][0];
    #pragma unroll
    for (int ks = 0; ks < 2; ++ks) {
      const int cc = (ks * 4 + l4) ^ swz7;
      short8 af[4], bfr[4];
      #pragma unroll
      for (int mi = 0; mi < 4; ++mi) af[mi]  = *(const short8*)&Ab[(wm*64 + mi*16 + l15)*64 + cc*8];
      #pragma unroll
      for (int ni = 0; ni < 4; ++ni) bfr[ni] = *(const short8*)&Bb[(wn*64 + ni*16 + l15)*64 + cc*8];
      __builtin_amdgcn_s_setprio(1);
      #pragma unroll
      for (int mi = 0; mi < 4; ++mi)
        #pragma unroll
        for (int ni = 0; ni < 4; ++ni)
          acc[mi][ni] = __builtin_amdgcn_mfma_f32_16x16x32_bf16(af[mi], bfr[ni], acc[mi][ni], 0, 0, 0);
      __builtin_amdgcn_s_setprio(0);
    }
    __syncthreads();
  }

  #pragma unroll
  for (int mi = 0; mi < 4; ++mi)
    #pragma unroll
    for (int ni = 0; ni < 4; ++ni)
      #pragma unroll
      for (int j = 0; j < 4; ++j) {
        int row = m0 + wm*64 + mi*16 + l4*4 + j;
        int col = n0 + wn*64 + ni*16 + l15;
        out[row * D_ + col] = acc[mi][ni][j];
      }
}

// ---------------- launcher ----------------
extern "C" void kernel_launch(void* const* d_in, const int* in_sizes, int n_in,
                              void* d_out, int out_size, void* d_ws, size_t ws_size,
                              hipStream_t stream)
{
  const float* x  = (const float*)d_in[0];
  const float* wq = (const float*)d_in[1];
  const float* wk = (const float*)d_in[2];
  const float* wv = (const float*)d_in[3];
  const float* wo = (const float*)d_in[4];
  const float* cs = (const float*)d_in[5];
  const int*  pos = (const int*)d_in[6];
  float* out = (float*)d_out;

  unsigned short* xb = (unsigned short*)d_out;   // d_out as scratch until final GEMM
  unsigned short* wb = xb + M_ * D_;

  unsigned short* qb  = (unsigned short*)d_ws;
  unsigned short* kbf = qb  + M_ * D_;
  unsigned short* vtb = kbf + M_ * D_;
  unsigned short* aob = vtb + M_ * D_;
  unsigned short* wob = qb;                      // dead q region after attn

  conv_kernel<<<dim3(2048), dim3(256), 0, stream>>>(x, wq, wk, wv, xb, wb);
  gemm_qkv_kernel<<<dim3(64, 24), dim3(256), 0, stream>>>(xb, wb, cs, pos, qb, kbf, vtb);
  attn_kernel<<<dim3(1024), dim3(256), 0, stream>>>(qb, kbf, vtb, aob);
  conv_wo_kernel<<<dim3(1024), dim3(256), 0, stream>>>(wo, wob);
  gemm_out_kernel<<<dim3(64, 8), dim3(256), 0, stream>>>(aob, wob, out);

  (void)in_sizes; (void)n_in; (void)out_size; (void)ws_size;
}

// Round 11
// 185.284 us; speedup vs baseline: 1.3714x; 1.3663x over previous
//
#include <hip/hip_runtime.h>

// ---------------- problem constants ----------------
constexpr int B_  = 4;
constexpr int S_  = 2048;
constexpr int D_  = 1024;
constexpr int H_  = 16;
constexpr int DK_ = 64;
constexpr int M_  = B_ * S_;          // 8192 token rows

typedef __attribute__((ext_vector_type(8))) short short8;
typedef __attribute__((ext_vector_type(4))) float f32x4;
typedef __attribute__((ext_vector_type(4))) unsigned short us4;
typedef __attribute__((ext_vector_type(4))) unsigned int u32x4;

__device__ __forceinline__ unsigned short f2b(float f) {
  unsigned int u = __float_as_uint(f);
  u += 0x7FFFu + ((u >> 16) & 1u);          // RNE
  return (unsigned short)(u >> 16);
}
__device__ __forceinline__ float b2f(unsigned short h) {
  return __uint_as_float(((unsigned int)h) << 16);
}
// packed f32x2 -> bf16x2 (RNE), single HW instr; low16 = src0
__device__ __forceinline__ unsigned int cvtpk(float lo, float hi) {
  unsigned int w;
  asm("v_cvt_pk_bf16_f32 %0, %1, %2" : "=v"(w) : "v"(lo), "v"(hi));
  return w;
}
// D = 2^S0
__device__ __forceinline__ float exp2v(float x) {
  float r;
  asm("v_exp_f32 %0, %1" : "=v"(r) : "v"(x));
  return r;
}

// async global->LDS, 16B per lane; LDS dest must be wave-uniform base (+ lane*16 by HW)
#define GLOAD16(g, l) __builtin_amdgcn_global_load_lds( \
    (const __attribute__((address_space(1))) unsigned int*)(g), \
    (__attribute__((address_space(3))) unsigned int*)(l), 16, 0, 0)

// ---------------- kernel 0: fp32 -> bf16 conversion (x, Wq|Wk|Wv) ----------------
__global__ __launch_bounds__(256) void conv_kernel(
    const float* __restrict__ x,
    const float* __restrict__ wq, const float* __restrict__ wk, const float* __restrict__ wv,
    unsigned short* __restrict__ xb, unsigned short* __restrict__ wb)
{
  const int NX4 = (M_ * D_) / 4;
  const int NW4 = (3 * D_ * D_) / 4;
  int stride = gridDim.x * blockDim.x;
  for (int i = blockIdx.x * blockDim.x + threadIdx.x; i < NX4 + NW4; i += stride) {
    const float4* src; unsigned short* dst; int o;
    if (i < NX4) { src = (const float4*)x; dst = xb; o = i; }
    else {
      int wi = i - NX4;
      int mat = wi >> 18;
      o = wi & 262143;
      src = (const float4*)(mat == 0 ? wq : (mat == 1 ? wk : wv));
      dst = wb + mat * (D_ * D_);
    }
    float4 v = src[o];
    us4 r; r.x = f2b(v.x); r.y = f2b(v.y); r.z = f2b(v.z); r.w = f2b(v.w);
    *(us4*)(dst + o * 4) = r;
  }
}

// ---------------- kernel 0b: Wo fp32 -> bf16 ----------------
__global__ __launch_bounds__(256) void conv_wo_kernel(
    const float* __restrict__ wo, unsigned short* __restrict__ wob)
{
  int i = blockIdx.x * 256 + threadIdx.x;       // 262144 float4s
  float4 v = ((const float4*)wo)[i];
  us4 r; r.x = f2b(v.x); r.y = f2b(v.y); r.z = f2b(v.z); r.w = f2b(v.w);
  *(us4*)(wob + i * 4) = r;
}

// ---------------- kernel 1: QKV projection GEMM (C = A * B^T) + fused RoPE -------------
__global__ __launch_bounds__(256, 2) void gemm_qkv_kernel(
    const unsigned short* __restrict__ xb,
    const unsigned short* __restrict__ wb,
    const float* __restrict__ cs,        // [2048][32][2] cos/sin
    const int* __restrict__ pos,
    unsigned short* __restrict__ qb,
    unsigned short* __restrict__ kb,
    unsigned short* __restrict__ vtb)
{
  __shared__ unsigned short As[2][128 * 64];   // 32 KB
  __shared__ unsigned short Bs[2][128 * 64];   // 32 KB
  const int tid  = threadIdx.x;
  const int lane = tid & 63;
  const int wid  = tid >> 6;
  const int wm = wid >> 1, wn = wid & 1;
  const int m0 = blockIdx.x * 128;
  const int n0 = blockIdx.y * 128;          // 0..3071
  const int l15 = lane & 15, l4 = lane >> 4;
  const int swz7 = l15 & 7;                 // frag-read swizzle (row&7 == l15&7)

  int srow[4], sgcc[4], slds[4];
  #pragma unroll
  for (int j = 0; j < 4; ++j) {
    int c = tid + j * 256;                  // chunk id 0..1023
    srow[j] = c >> 3;                       // row 0..127
    int cc  = c & 7;
    sgcc[j] = cc ^ (srow[j] & 7);           // inverse-swizzled global col-chunk
    slds[j] = (wid * 64 + j * 256) * 8;     // wave-uniform LDS base (shorts)
  }

  f32x4 acc[4][4] = {};

  #pragma unroll
  for (int j = 0; j < 4; ++j) {
    GLOAD16(xb + (m0 + srow[j]) * D_ + sgcc[j] * 8, &As[0][slds[j]]);
    GLOAD16(wb + (n0 + srow[j]) * D_ + sgcc[j] * 8, &Bs[0][slds[j]]);
  }
  __syncthreads();

  for (int t = 0; t < 16; ++t) {
    const int cur = t & 1, nxt = cur ^ 1;
    if (t < 15) {                           // stage-early: issue next tile under compute
      const int kcol = (t + 1) * 64;
      #pragma unroll
      for (int j = 0; j < 4; ++j) {
        GLOAD16(xb + (m0 + srow[j]) * D_ + kcol + sgcc[j] * 8, &As[nxt][slds[j]]);
        GLOAD16(wb + (n0 + srow[j]) * D_ + kcol + sgcc[j] * 8, &Bs[nxt][slds[j]]);
      }
    }
    const unsigned short* Ab = &As[cur][0];
    const unsigned short* Bb = &Bs[cur][0];
    #pragma unroll
    for (int ks = 0; ks < 2; ++ks) {
      const int cc = (ks * 4 + l4) ^ swz7;  // swizzled chunk within row
      short8 af[4], bfr[4];
      #pragma unroll
      for (int mi = 0; mi < 4; ++mi) af[mi]  = *(const short8*)&Ab[(wm*64 + mi*16 + l15)*64 + cc*8];
      #pragma unroll
      for (int ni = 0; ni < 4; ++ni) bfr[ni] = *(const short8*)&Bb[(wn*64 + ni*16 + l15)*64 + cc*8];
      __builtin_amdgcn_s_setprio(1);
      #pragma unroll
      for (int mi = 0; mi < 4; ++mi)
        #pragma unroll
        for (int ni = 0; ni < 4; ++ni)
          acc[mi][ni] = __builtin_amdgcn_mfma_f32_16x16x32_bf16(af[mi], bfr[ni], acc[mi][ni], 0, 0, 0);
      __builtin_amdgcn_s_setprio(0);
    }
    __syncthreads();                        // drains vmcnt (next tile landed) + joins
  }

  const int bidx = m0 >> 11;
  const int sbase = (m0 & 2047) + wm * 64;

  if (n0 < 2048) {
    // ---- q or k block: fused RoPE, [b][h][s][d] scatter ----
    unsigned short* dst = (n0 < 1024) ? qb : kb;
    const int nn0 = n0 & 1023;
    const float2* cs2 = (const float2*)cs;
    const float sg = (l15 & 1) ? 1.0f : -1.0f;
    #pragma unroll
    for (int mi = 0; mi < 4; ++mi)
      #pragma unroll
      for (int j = 0; j < 4; ++j) {
        int s = sbase + mi*16 + l4*4 + j;
        int p = pos[s];
        #pragma unroll
        for (int ni = 0; ni < 4; ++ni) {
          int col = nn0 + wn*64 + ni*16 + l15;
          int h = col >> 6, dd = col & 63;
          float val = acc[mi][ni][j];
          float par = __shfl_xor(val, 1);
          float2 cv = cs2[p*32 + (dd >> 1)];
          float r = fmaf(cv.x, val, sg * cv.y * par);
          dst[((bidx*H_ + h)*S_ + s)*DK_ + dd] = f2b(r);
        }
      }
  } else {
    // ---- v block: transposed scatter [b][h][d][s]; 8B packed stores ----
    const int nn0 = n0 & 1023;
    const int hB = (nn0 + wn*64) >> 6;
    #pragma unroll
    for (int mi = 0; mi < 4; ++mi) {
      int s4 = sbase + mi*16 + l4*4;
      #pragma unroll
      for (int ni = 0; ni < 4; ++ni) {
        int dd = ni*16 + l15;
        uint2 w;
        w.x = cvtpk(acc[mi][ni][0], acc[mi][ni][1]);
        w.y = cvtpk(acc[mi][ni][2], acc[mi][ni][3]);
        *(uint2*)(vtb + ((bidx*H_ + hB)*DK_ + dd)*S_ + s4) = w;
      }
    }
  }
}

// ---------------- kernel 3: causal flash attention v7c ----------------
// v7b structure; __launch_bounds__(256,4): the (256,5) bound capped the unified
// VGPR+AGPR budget at ~96 and forced ~20-reg spills to scratch (219MB WRITE_SIZE,
// rounds 9-10). 4 waves/SIMD -> 128-reg budget, no spill.
__global__ __launch_bounds__(256, 4) void attn_kernel(
    const unsigned short* __restrict__ qb,
    const unsigned short* __restrict__ kb,
    const unsigned short* __restrict__ vtb,
    unsigned short* __restrict__ ao)
{
  __shared__ unsigned short Ks[2][64 * 64];    // [key][dim] linear, chunk-swizzled
  __shared__ unsigned short Vs[2][64 * 64];    // [dim][key] linear, chunk-swizzled
  const int tid = threadIdx.x, lane = tid & 63, wid = tid >> 6;
  const int l15 = lane & 15, l4 = lane >> 4;
  const int swz7 = l15 & 7;

  const int id  = blockIdx.x;                  // 0..1023
  const int xcd = id & 7, rem = id >> 3;       // rem: 0..127
  const int bh  = xcd * 8 + (rem & 7);         // 8 consecutive heads per XCD
  const int qt  = 15 - (rem >> 3);             // heavy q-tiles dispatched first
  const int q0  = qt * 128;
  const int nkt = 2 * qt + 2;

  const unsigned short* qp = qb  + bh * S_ * DK_;
  const unsigned short* kp = kb  + bh * S_ * DK_;
  const unsigned short* vp = vtb + bh * DK_ * S_;
  const int bidx = bh >> 4, h = bh & 15;

  // staging geometry: 512 chunks of 16B per matrix per tile; 2 chunks/thread
  int srow[2], sgcc[2], slds[2];
  #pragma unroll
  for (int j = 0; j < 2; ++j) {
    int c = tid + j * 256;                     // chunk id 0..511
    srow[j] = c >> 3;                          // row 0..63 (K: key, V: dim)
    int cc  = c & 7;
    sgcc[j] = cc ^ (srow[j] & 7);              // inverse-swizzled global col-chunk
    slds[j] = (wid * 64 + j * 256) * 8;        // wave-uniform LDS base (shorts)
  }

  // Q B-frags, two 16-row groups per wave, pre-scaled by (1/8)*log2(e)
  const float QSC = 0.18033688f;
  short8 qf[2][2];
  #pragma unroll
  for (int y = 0; y < 2; ++y)
    #pragma unroll
    for (int kbk = 0; kbk < 2; ++kbk) {
      short8 raw = *(const short8*)(qp + (q0 + y*64 + wid*16 + l15)*DK_ + kbk*32 + l4*8);
      #pragma unroll
      for (int i = 0; i < 8; ++i) {
        float f = b2f((unsigned short)raw[i]) * QSC;
        raw[i] = (short)f2b(f);
      }
      qf[y][kbk] = raw;
    }

  f32x4 oacc[2][4] = {};
  float mrun[2] = {-1e30f, -1e30f}, lrun[2] = {0.0f, 0.0f};

  // prologue: stage tile 0 -> buf 0
  #pragma unroll
  for (int j = 0; j < 2; ++j) {
    GLOAD16(kp + srow[j]*DK_ + sgcc[j]*8, &Ks[0][slds[j]]);
    GLOAD16(vp + srow[j]*S_  + sgcc[j]*8, &Vs[0][slds[j]]);
  }
  __syncthreads();                             // vmcnt drained: tile 0 visible

  const int vhalf = (l4 & 1) * 4;              // b64 half within 16B chunk (shorts)
  const int g0 = l4 >> 1;                      // chunk of keys l4*4..l4*4+3
  for (int kt = 0; kt < nkt; ++kt) {
    const int cur = kt & 1, nxt = cur ^ 1;
    if (kt + 1 < nkt) {                        // stage-early: next tile under compute
      const int kb0 = (kt + 1) * 64;
      #pragma unroll
      for (int j = 0; j < 2; ++j) {
        GLOAD16(kp + (kb0 + srow[j])*DK_ + sgcc[j]*8, &Ks[nxt][slds[j]]);
        GLOAD16(vp + srow[j]*S_ + kb0   + sgcc[j]*8, &Vs[nxt][slds[j]]);
      }
    }

    #pragma unroll
    for (int y = 0; y < 2; ++y) {
      if (kt > 2*qt + y) continue;             // fully masked group

      // swapped QK^T: lane owns q-row (l15), 16 keys in-register
      f32x4 sc[4];
      __builtin_amdgcn_s_setprio(1);
      #pragma unroll
      for (int nb = 0; nb < 4; ++nb) {
        const int rb = (nb*16 + l15) * 64;
        short8 k0 = *(const short8*)&Ks[cur][rb + ((l4     ^ swz7) * 8)];
        short8 k1 = *(const short8*)&Ks[cur][rb + (((4+l4) ^ swz7) * 8)];
        f32x4 z = {};
        z = __builtin_amdgcn_mfma_f32_16x16x32_bf16(k0, qf[y][0], z, 0, 0, 0);
        z = __builtin_amdgcn_mfma_f32_16x16x32_bf16(k1, qf[y][1], z, 0, 0, 0);
        sc[nb] = z;
      }
      __builtin_amdgcn_s_setprio(0);

      if (kt == 2*qt + y) {                    // diagonal tile mask
        const int qg = q0 + y*64 + wid*16 + l15;
        #pragma unroll
        for (int nb = 0; nb < 4; ++nb)
          #pragma unroll
          for (int j = 0; j < 4; ++j) {
            int kg = kt*64 + nb*16 + l4*4 + j;
            if (kg > qg) sc[nb][j] = -1e30f;
          }
      }

      // online softmax in log2 domain, defer-max THR=8; tree reductions
      float mq[4];
      #pragma unroll
      for (int nb = 0; nb < 4; ++nb)
        mq[nb] = fmaxf(fmaxf(sc[nb][0], sc[nb][1]), fmaxf(sc[nb][2], sc[nb][3]));
      float tm = fmaxf(fmaxf(mq[0], mq[1]), fmaxf(mq[2], mq[3]));
      tm = fmaxf(tm, __shfl_xor(tm, 16));
      tm = fmaxf(tm, __shfl_xor(tm, 32));
      if (!__all(tm - mrun[y] <= 8.0f)) {
        float mnew = fmaxf(mrun[y], tm);
        float corr = exp2v(mrun[y] - mnew);
        mrun[y] = mnew;
        lrun[y] *= corr;
        #pragma unroll
        for (int j = 0; j < 4; ++j) {
          float cj = __shfl(corr, l4*4 + j);
          #pragma unroll
          for (int nb = 0; nb < 4; ++nb) oacc[y][nb][j] *= cj;
        }
      }
      float sq[4];
      #pragma unroll
      for (int nb = 0; nb < 4; ++nb) {
        #pragma unroll
        for (int j = 0; j < 4; ++j) sc[nb][j] = exp2v(sc[nb][j] - mrun[y]);
        sq[nb] = (sc[nb][0] + sc[nb][1]) + (sc[nb][2] + sc[nb][3]);
      }
      float rs = (sq[0] + sq[1]) + (sq[2] + sq[3]);
      rs += __shfl_xor(rs, 16);
      rs += __shfl_xor(rs, 32);
      lrun[y] += rs;

      // P -> A-frags IN-REGISTER via vector literals + bit_cast (no scratch)
      u32x4 pa0v = { cvtpk(sc[0][0], sc[0][1]), cvtpk(sc[0][2], sc[0][3]),
                     cvtpk(sc[1][0], sc[1][1]), cvtpk(sc[1][2], sc[1][3]) };
      u32x4 pa1v = { cvtpk(sc[2][0], sc[2][1]), cvtpk(sc[2][2], sc[2][3]),
                     cvtpk(sc[3][0], sc[3][1]), cvtpk(sc[3][2], sc[3][3]) };
      short8 pa0 = __builtin_bit_cast(short8, pa0v);
      short8 pa1 = __builtin_bit_cast(short8, pa1v);

      // O += P * V  (V b64 reads in the SAME permuted key order, chunk-swizzled)
      __builtin_amdgcn_s_setprio(1);
      #pragma unroll
      for (int nb = 0; nb < 4; ++nb) {
        const int rb = (nb*16 + l15) * 64;
        uint2 a0 = *(const uint2*)&Vs[cur][rb + (( g0      ^ swz7) * 8) + vhalf];
        uint2 a1 = *(const uint2*)&Vs[cur][rb + (((2 + g0) ^ swz7) * 8) + vhalf];
        uint2 b0 = *(const uint2*)&Vs[cur][rb + (((4 + g0) ^ swz7) * 8) + vhalf];
        uint2 b1 = *(const uint2*)&Vs[cur][rb + (((6 + g0) ^ swz7) * 8) + vhalf];
        u32x4 v0v = { a0.x, a0.y, a1.x, a1.y };
        u32x4 v1v = { b0.x, b0.y, b1.x, b1.y };
        short8 v0 = __builtin_bit_cast(short8, v0v);
        short8 v1 = __builtin_bit_cast(short8, v1v);
        oacc[y][nb] = __builtin_amdgcn_mfma_f32_16x16x32_bf16(pa0, v0, oacc[y][nb], 0, 0, 0);
        oacc[y][nb] = __builtin_amdgcn_mfma_f32_16x16x32_bf16(pa1, v1, oacc[y][nb], 0, 0, 0);
      }
      __builtin_amdgcn_s_setprio(0);
    }

    __syncthreads();                           // drains vmcnt (nxt staged) + joins
  }

  #pragma unroll
  for (int y = 0; y < 2; ++y)
    #pragma unroll
    for (int j = 0; j < 4; ++j) {
      float lj = __shfl(lrun[y], l4*4 + j);
      float inv = 1.0f / lj;
      int row = q0 + y*64 + wid*16 + l4*4 + j;
      #pragma unroll
      for (int nb = 0; nb < 4; ++nb) {
        int dim = nb*16 + l15;
        ao[((bidx*S_ + row)*H_ + h)*DK_ + dim] = f2b(oacc[y][nb][j] * inv);
      }
    }
}

// ---------------- kernel 4: output projection (C = A * Wo^T), fp32 out -----------------
__global__ __launch_bounds__(256, 2) void gemm_out_kernel(
    const unsigned short* __restrict__ ao,
    const unsigned short* __restrict__ wob,
    float* __restrict__ out)
{
  __shared__ unsigned short As[2][128 * 64];
  __shared__ unsigned short Bs[2][128 * 64];
  const int tid = threadIdx.x, lane = tid & 63, wid = tid >> 6;
  const int wm = wid >> 1, wn = wid & 1;
  const int m0 = blockIdx.x * 128, n0 = blockIdx.y * 128;
  const int l15 = lane & 15, l4 = lane >> 4;
  const int swz7 = l15 & 7;

  int srow[4], sgcc[4], slds[4];
  #pragma unroll
  for (int j = 0; j < 4; ++j) {
    int c = tid + j * 256;
    srow[j] = c >> 3;
    int cc  = c & 7;
    sgcc[j] = cc ^ (srow[j] & 7);
    slds[j] = (wid * 64 + j * 256) * 8;
  }

  f32x4 acc[4][4] = {};

  #pragma unroll
  for (int j = 0; j < 4; ++j) {
    GLOAD16(ao  + (m0 + srow[j]) * D_ + sgcc[j] * 8, &As[0][slds[j]]);
    GLOAD16(wob + (n0 + srow[j]) * D_ + sgcc[j] * 8, &Bs[0][slds[j]]);
  }
  __syncthreads();

  for (int t = 0; t < 16; ++t) {
    const int cur = t & 1, nxt = cur ^ 1;
    if (t < 15) {
      const int kcol = (t + 1) * 64;
      #pragma unroll
      for (int j = 0; j < 4; ++j) {
        GLOAD16(ao  + (m0 + srow[j]) * D_ + kcol + sgcc[j] * 8, &As[nxt][slds[j]]);
        GLOAD16(wob + (n0 + srow[j]) * D_ + kcol + sgcc[j] * 8, &Bs[nxt][slds[j]]);
      }
    }
    const unsigned short* Ab = &As[cur][0];
    const unsigned short* Bb = &Bs[cur][0];
    #pragma unroll
    for (int ks = 0; ks < 2; ++ks) {
      const int cc = (ks * 4 + l4) ^ swz7;
      short8 af[4], bfr[4];
      #pragma unroll
      for (int mi = 0; mi < 4; ++mi) af[mi]  = *(const short8*)&Ab[(wm*64 + mi*16 + l15)*64 + cc*8];
      #pragma unroll
      for (int ni = 0; ni < 4; ++ni) bfr[ni] = *(const short8*)&Bb[(wn*64 + ni*16 + l15)*64 + cc*8];
      __builtin_amdgcn_s_setprio(1);
      #pragma unroll
      for (int mi = 0; mi < 4; ++mi)
        #pragma unroll
        for (int ni = 0; ni < 4; ++ni)
          acc[mi][ni] = __builtin_amdgcn_mfma_f32_16x16x32_bf16(af[mi], bfr[ni], acc[mi][ni], 0, 0, 0);
      __builtin_amdgcn_s_setprio(0);
    }
    __syncthreads();
  }

  #pragma unroll
  for (int mi = 0; mi < 4; ++mi)
    #pragma unroll
    for (int ni = 0; ni < 4; ++ni)
      #pragma unroll
      for (int j = 0; j < 4; ++j) {
        int row = m0 + wm*64 + mi*16 + l4*4 + j;
        int col = n0 + wn*64 + ni*16 + l15;
        out[row * D_ + col] = acc[mi][ni][j];
      }
}

// ---------------- launcher ----------------
extern "C" void kernel_launch(void* const* d_in, const int* in_sizes, int n_in,
                              void* d_out, int out_size, void* d_ws, size_t ws_size,
                              hipStream_t stream)
{
  const float* x  = (const float*)d_in[0];
  const float* wq = (const float*)d_in[1];
  const float* wk = (const float*)d_in[2];
  const float* wv = (const float*)d_in[3];
  const float* wo = (const float*)d_in[4];
  const float* cs = (const float*)d_in[5];
  const int*  pos = (const int*)d_in[6];
  float* out = (float*)d_out;

  unsigned short* xb = (unsigned short*)d_out;   // d_out as scratch until final GEMM
  unsigned short* wb = xb + M_ * D_;

  unsigned short* qb  = (unsigned short*)d_ws;
  unsigned short* kbf = qb  + M_ * D_;
  unsigned short* vtb = kbf + M_ * D_;
  unsigned short* aob = vtb + M_ * D_;
  unsigned short* wob = qb;                      // dead q region after attn

  conv_kernel<<<dim3(2048), dim3(256), 0, stream>>>(x, wq, wk, wv, xb, wb);
  gemm_qkv_kernel<<<dim3(64, 24), dim3(256), 0, stream>>>(xb, wb, cs, pos, qb, kbf, vtb);
  attn_kernel<<<dim3(1024), dim3(256), 0, stream>>>(qb, kbf, vtb, aob);
  conv_wo_kernel<<<dim3(1024), dim3(256), 0, stream>>>(wo, wob);
  gemm_out_kernel<<<dim3(64, 8), dim3(256), 0, stream>>>(aob, wob, out);

  (void)in_sizes; (void)n_in; (void)out_size; (void)ws_size;
}

// Round 12
// 171.714 us; speedup vs baseline: 1.4798x; 1.0790x over previous
//
#include <hip/hip_runtime.h>

// ---------------- problem constants ----------------
constexpr int B_  = 4;
constexpr int S_  = 2048;
constexpr int D_  = 1024;
constexpr int H_  = 16;
constexpr int DK_ = 64;
constexpr int M_  = B_ * S_;          // 8192 token rows

typedef __attribute__((ext_vector_type(8))) short short8;
typedef __attribute__((ext_vector_type(4))) float f32x4;
typedef __attribute__((ext_vector_type(4))) unsigned short us4;
typedef __attribute__((ext_vector_type(4))) unsigned int u32x4;

__device__ __forceinline__ unsigned short f2b(float f) {
  unsigned int u = __float_as_uint(f);
  u += 0x7FFFu + ((u >> 16) & 1u);          // RNE
  return (unsigned short)(u >> 16);
}
__device__ __forceinline__ float b2f(unsigned short h) {
  return __uint_as_float(((unsigned int)h) << 16);
}
// packed f32x2 -> bf16x2 (RNE), single HW instr; low16 = src0
__device__ __forceinline__ unsigned int cvtpk(float lo, float hi) {
  unsigned int w;
  asm("v_cvt_pk_bf16_f32 %0, %1, %2" : "=v"(w) : "v"(lo), "v"(hi));
  return w;
}
// D = 2^S0
__device__ __forceinline__ float exp2v(float x) {
  float r;
  asm("v_exp_f32 %0, %1" : "=v"(r) : "v"(x));
  return r;
}

// async global->LDS, 16B per lane; LDS dest must be wave-uniform base (+ lane*16 by HW)
#define GLOAD16(g, l) __builtin_amdgcn_global_load_lds( \
    (const __attribute__((address_space(1))) unsigned int*)(g), \
    (__attribute__((address_space(3))) unsigned int*)(l), 16, 0, 0)

// ---------------- kernel 0: fp32 -> bf16 conversion (x, Wq|Wk|Wv) ----------------
__global__ __launch_bounds__(256) void conv_kernel(
    const float* __restrict__ x,
    const float* __restrict__ wq, const float* __restrict__ wk, const float* __restrict__ wv,
    unsigned short* __restrict__ xb, unsigned short* __restrict__ wb)
{
  const int NX4 = (M_ * D_) / 4;
  const int NW4 = (3 * D_ * D_) / 4;
  int stride = gridDim.x * blockDim.x;
  for (int i = blockIdx.x * blockDim.x + threadIdx.x; i < NX4 + NW4; i += stride) {
    const float4* src; unsigned short* dst; int o;
    if (i < NX4) { src = (const float4*)x; dst = xb; o = i; }
    else {
      int wi = i - NX4;
      int mat = wi >> 18;
      o = wi & 262143;
      src = (const float4*)(mat == 0 ? wq : (mat == 1 ? wk : wv));
      dst = wb + mat * (D_ * D_);
    }
    float4 v = src[o];
    us4 r; r.x = f2b(v.x); r.y = f2b(v.y); r.z = f2b(v.z); r.w = f2b(v.w);
    *(us4*)(dst + o * 4) = r;
  }
}

// ---------------- kernel 0b: Wo fp32 -> bf16 ----------------
__global__ __launch_bounds__(256) void conv_wo_kernel(
    const float* __restrict__ wo, unsigned short* __restrict__ wob)
{
  int i = blockIdx.x * 256 + threadIdx.x;       // 262144 float4s
  float4 v = ((const float4*)wo)[i];
  us4 r; r.x = f2b(v.x); r.y = f2b(v.y); r.z = f2b(v.z); r.w = f2b(v.w);
  *(us4*)(wob + i * 4) = r;
}

// ---------------- kernel 1: QKV projection GEMM (C = A * B^T) + fused RoPE -------------
// v stored with PERMUTED key order: within each 32-key group, 16B chunk c holds keys
// [4c..4c+3, 16+4c..16+4c+3] -> attn's in-register-P PV reads are plain b128 chunks.
__global__ __launch_bounds__(256, 2) void gemm_qkv_kernel(
    const unsigned short* __restrict__ xb,
    const unsigned short* __restrict__ wb,
    const float* __restrict__ cs,        // [2048][32][2] cos/sin
    const int* __restrict__ pos,
    unsigned short* __restrict__ qb,
    unsigned short* __restrict__ kb,
    unsigned short* __restrict__ vtb)
{
  __shared__ unsigned short As[2][128 * 64];   // 32 KB
  __shared__ unsigned short Bs[2][128 * 64];   // 32 KB
  const int tid  = threadIdx.x;
  const int lane = tid & 63;
  const int wid  = tid >> 6;
  const int wm = wid >> 1, wn = wid & 1;
  const int m0 = blockIdx.x * 128;
  const int n0 = blockIdx.y * 128;          // 0..3071
  const int l15 = lane & 15, l4 = lane >> 4;
  const int swz7 = l15 & 7;                 // frag-read swizzle (row&7 == l15&7)

  int srow[4], sgcc[4], slds[4];
  #pragma unroll
  for (int j = 0; j < 4; ++j) {
    int c = tid + j * 256;                  // chunk id 0..1023
    srow[j] = c >> 3;                       // row 0..127
    int cc  = c & 7;
    sgcc[j] = cc ^ (srow[j] & 7);           // inverse-swizzled global col-chunk
    slds[j] = (wid * 64 + j * 256) * 8;     // wave-uniform LDS base (shorts)
  }

  f32x4 acc[4][4] = {};

  #pragma unroll
  for (int j = 0; j < 4; ++j) {
    GLOAD16(xb + (m0 + srow[j]) * D_ + sgcc[j] * 8, &As[0][slds[j]]);
    GLOAD16(wb + (n0 + srow[j]) * D_ + sgcc[j] * 8, &Bs[0][slds[j]]);
  }
  __syncthreads();

  for (int t = 0; t < 16; ++t) {
    const int cur = t & 1, nxt = cur ^ 1;
    if (t < 15) {                           // stage-early: issue next tile under compute
      const int kcol = (t + 1) * 64;
      #pragma unroll
      for (int j = 0; j < 4; ++j) {
        GLOAD16(xb + (m0 + srow[j]) * D_ + kcol + sgcc[j] * 8, &As[nxt][slds[j]]);
        GLOAD16(wb + (n0 + srow[j]) * D_ + kcol + sgcc[j] * 8, &Bs[nxt][slds[j]]);
      }
    }
    const unsigned short* Ab = &As[cur][0];
    const unsigned short* Bb = &Bs[cur][0];
    #pragma unroll
    for (int ks = 0; ks < 2; ++ks) {
      const int cc = (ks * 4 + l4) ^ swz7;  // swizzled chunk within row
      short8 af[4], bfr[4];
      #pragma unroll
      for (int mi = 0; mi < 4; ++mi) af[mi]  = *(const short8*)&Ab[(wm*64 + mi*16 + l15)*64 + cc*8];
      #pragma unroll
      for (int ni = 0; ni < 4; ++ni) bfr[ni] = *(const short8*)&Bb[(wn*64 + ni*16 + l15)*64 + cc*8];
      __builtin_amdgcn_s_setprio(1);
      #pragma unroll
      for (int mi = 0; mi < 4; ++mi)
        #pragma unroll
        for (int ni = 0; ni < 4; ++ni)
          acc[mi][ni] = __builtin_amdgcn_mfma_f32_16x16x32_bf16(af[mi], bfr[ni], acc[mi][ni], 0, 0, 0);
      __builtin_amdgcn_s_setprio(0);
    }
    __syncthreads();                        // drains vmcnt (next tile landed) + joins
  }

  const int bidx = m0 >> 11;
  const int sbase = (m0 & 2047) + wm * 64;

  if (n0 < 2048) {
    // ---- q or k block: fused RoPE, [b][h][s][d] scatter ----
    unsigned short* dst = (n0 < 1024) ? qb : kb;
    const int nn0 = n0 & 1023;
    const float2* cs2 = (const float2*)cs;
    const float sg = (l15 & 1) ? 1.0f : -1.0f;
    #pragma unroll
    for (int mi = 0; mi < 4; ++mi)
      #pragma unroll
      for (int j = 0; j < 4; ++j) {
        int s = sbase + mi*16 + l4*4 + j;
        int p = pos[s];
        #pragma unroll
        for (int ni = 0; ni < 4; ++ni) {
          int col = nn0 + wn*64 + ni*16 + l15;
          int h = col >> 6, dd = col & 63;
          float val = acc[mi][ni][j];
          float par = __shfl_xor(val, 1);
          float2 cv = cs2[p*32 + (dd >> 1)];
          float r = fmaf(cv.x, val, sg * cv.y * par);
          dst[((bidx*H_ + h)*S_ + s)*DK_ + dd] = f2b(r);
        }
      }
  } else {
    // ---- v block: transposed scatter [b][h][d][s_permuted]; 8B packed stores.
    // Key-permute within each 32-key group: granule a (4 keys) at b=a&7 moves to
    // granule 2*(b&3)+(b>>2) -> chunk c holds keys [4c..4c+3, 16+4c..16+4c+3].
    const int nn0 = n0 & 1023;
    const int hB = (nn0 + wn*64) >> 6;
    #pragma unroll
    for (int mi = 0; mi < 4; ++mi) {
      int s4 = sbase + mi*16 + l4*4;
      int a  = s4 >> 2, bgr = a & 7;
      int s4p = ((a & ~7) + ((bgr & 3)*2 + (bgr >> 2))) << 2;
      #pragma unroll
      for (int ni = 0; ni < 4; ++ni) {
        int dd = ni*16 + l15;
        uint2 w;
        w.x = cvtpk(acc[mi][ni][0], acc[mi][ni][1]);
        w.y = cvtpk(acc[mi][ni][2], acc[mi][ni][3]);
        *(uint2*)(vtb + ((bidx*H_ + hB)*DK_ + dd)*S_ + s4p) = w;
      }
    }
  }
}

// ---------------- kernel 3: causal flash attention v7d ----------------
// In-register P (permuted MFMA K-slots) + key-permuted V layout so PV reads are two
// ds_read_b128 per fragment (same balanced pattern as K reads). No Ps buffer, no
// lgkmcnt(0) drain. launch_bounds(256,4) (5 caused spill, rounds 9-10).
__global__ __launch_bounds__(256, 4) void attn_kernel(
    const unsigned short* __restrict__ qb,
    const unsigned short* __restrict__ kb,
    const unsigned short* __restrict__ vtb,
    unsigned short* __restrict__ ao)
{
  __shared__ unsigned short Ks[2][64 * 64];    // [key][dim] linear, chunk-swizzled
  __shared__ unsigned short Vs[2][64 * 64];    // [dim][key_permuted] linear, chunk-swizzled
  const int tid = threadIdx.x, lane = tid & 63, wid = tid >> 6;
  const int l15 = lane & 15, l4 = lane >> 4;
  const int swz7 = l15 & 7;

  const int id  = blockIdx.x;                  // 0..1023
  const int xcd = id & 7, rem = id >> 3;       // rem: 0..127
  const int bh  = xcd * 8 + (rem & 7);         // 8 consecutive heads per XCD
  const int qt  = 15 - (rem >> 3);             // heavy q-tiles dispatched first
  const int q0  = qt * 128;
  const int nkt = 2 * qt + 2;

  const unsigned short* qp = qb  + bh * S_ * DK_;
  const unsigned short* kp = kb  + bh * S_ * DK_;
  const unsigned short* vp = vtb + bh * DK_ * S_;
  const int bidx = bh >> 4, h = bh & 15;

  // staging geometry: 512 chunks of 16B per matrix per tile; 2 chunks/thread
  int srow[2], sgcc[2], slds[2];
  #pragma unroll
  for (int j = 0; j < 2; ++j) {
    int c = tid + j * 256;                     // chunk id 0..511
    srow[j] = c >> 3;                          // row 0..63 (K: key, V: dim)
    int cc  = c & 7;
    sgcc[j] = cc ^ (srow[j] & 7);              // inverse-swizzled global col-chunk
    slds[j] = (wid * 64 + j * 256) * 8;        // wave-uniform LDS base (shorts)
  }

  // Q B-frags, two 16-row groups per wave, pre-scaled by (1/8)*log2(e)
  const float QSC = 0.18033688f;
  short8 qf[2][2];
  #pragma unroll
  for (int y = 0; y < 2; ++y)
    #pragma unroll
    for (int kbk = 0; kbk < 2; ++kbk) {
      short8 raw = *(const short8*)(qp + (q0 + y*64 + wid*16 + l15)*DK_ + kbk*32 + l4*8);
      #pragma unroll
      for (int i = 0; i < 8; ++i) {
        float f = b2f((unsigned short)raw[i]) * QSC;
        raw[i] = (short)f2b(f);
      }
      qf[y][kbk] = raw;
    }

  f32x4 oacc[2][4] = {};
  float mrun[2] = {-1e30f, -1e30f}, lrun[2] = {0.0f, 0.0f};

  // prologue: stage tile 0 -> buf 0
  #pragma unroll
  for (int j = 0; j < 2; ++j) {
    GLOAD16(kp + srow[j]*DK_ + sgcc[j]*8, &Ks[0][slds[j]]);
    GLOAD16(vp + srow[j]*S_  + sgcc[j]*8, &Vs[0][slds[j]]);
  }
  __syncthreads();                             // vmcnt drained: tile 0 visible

  for (int kt = 0; kt < nkt; ++kt) {
    const int cur = kt & 1, nxt = cur ^ 1;
    if (kt + 1 < nkt) {                        // stage-early: next tile under compute
      const int kb0 = (kt + 1) * 64;
      #pragma unroll
      for (int j = 0; j < 2; ++j) {
        GLOAD16(kp + (kb0 + srow[j])*DK_ + sgcc[j]*8, &Ks[nxt][slds[j]]);
        GLOAD16(vp + srow[j]*S_ + kb0   + sgcc[j]*8, &Vs[nxt][slds[j]]);
      }
    }

    #pragma unroll
    for (int y = 0; y < 2; ++y) {
      if (kt > 2*qt + y) continue;             // fully masked group

      // swapped QK^T: lane owns q-row (l15), 16 keys in-register
      f32x4 sc[4];
      __builtin_amdgcn_s_setprio(1);
      #pragma unroll
      for (int nb = 0; nb < 4; ++nb) {
        const int rb = (nb*16 + l15) * 64;
        short8 k0 = *(const short8*)&Ks[cur][rb + ((l4     ^ swz7) * 8)];
        short8 k1 = *(const short8*)&Ks[cur][rb + (((4+l4) ^ swz7) * 8)];
        f32x4 z = {};
        z = __builtin_amdgcn_mfma_f32_16x16x32_bf16(k0, qf[y][0], z, 0, 0, 0);
        z = __builtin_amdgcn_mfma_f32_16x16x32_bf16(k1, qf[y][1], z, 0, 0, 0);
        sc[nb] = z;
      }
      __builtin_amdgcn_s_setprio(0);

      if (kt == 2*qt + y) {                    // diagonal tile mask
        const int qg = q0 + y*64 + wid*16 + l15;
        #pragma unroll
        for (int nb = 0; nb < 4; ++nb)
          #pragma unroll
          for (int j = 0; j < 4; ++j) {
            int kg = kt*64 + nb*16 + l4*4 + j;
            if (kg > qg) sc[nb][j] = -1e30f;
          }
      }

      // online softmax in log2 domain, defer-max THR=8; tree reductions
      float mq[4];
      #pragma unroll
      for (int nb = 0; nb < 4; ++nb)
        mq[nb] = fmaxf(fmaxf(sc[nb][0], sc[nb][1]), fmaxf(sc[nb][2], sc[nb][3]));
      float tm = fmaxf(fmaxf(mq[0], mq[1]), fmaxf(mq[2], mq[3]));
      tm = fmaxf(tm, __shfl_xor(tm, 16));
      tm = fmaxf(tm, __shfl_xor(tm, 32));
      if (!__all(tm - mrun[y] <= 8.0f)) {
        float mnew = fmaxf(mrun[y], tm);
        float corr = exp2v(mrun[y] - mnew);
        mrun[y] = mnew;
        lrun[y] *= corr;
        #pragma unroll
        for (int j = 0; j < 4; ++j) {
          float cj = __shfl(corr, l4*4 + j);
          #pragma unroll
          for (int nb = 0; nb < 4; ++nb) oacc[y][nb][j] *= cj;
        }
      }
      float sq[4];
      #pragma unroll
      for (int nb = 0; nb < 4; ++nb) {
        #pragma unroll
        for (int j = 0; j < 4; ++j) sc[nb][j] = exp2v(sc[nb][j] - mrun[y]);
        sq[nb] = (sc[nb][0] + sc[nb][1]) + (sc[nb][2] + sc[nb][3]);
      }
      float rs = (sq[0] + sq[1]) + (sq[2] + sq[3]);
      rs += __shfl_xor(rs, 16);
      rs += __shfl_xor(rs, 32);
      lrun[y] += rs;

      // P -> A-frags IN-REGISTER (key order l4*4+j then 16+l4*4+j, matching V chunks)
      u32x4 pa0v = { cvtpk(sc[0][0], sc[0][1]), cvtpk(sc[0][2], sc[0][3]),
                     cvtpk(sc[1][0], sc[1][1]), cvtpk(sc[1][2], sc[1][3]) };
      u32x4 pa1v = { cvtpk(sc[2][0], sc[2][1]), cvtpk(sc[2][2], sc[2][3]),
                     cvtpk(sc[3][0], sc[3][1]), cvtpk(sc[3][2], sc[3][3]) };
      short8 pa0 = __builtin_bit_cast(short8, pa0v);
      short8 pa1 = __builtin_bit_cast(short8, pa1v);

      // O += P * V: V chunk (l4^swz7) holds keys [l4*4..+3, 16+l4*4..+3] (permuted
      // global layout) -> single b128 per fragment, same balanced pattern as K.
      __builtin_amdgcn_s_setprio(1);
      #pragma unroll
      for (int nb = 0; nb < 4; ++nb) {
        const int rb = (nb*16 + l15) * 64;
        short8 v0 = *(const short8*)&Vs[cur][rb + ((l4     ^ swz7) * 8)];
        short8 v1 = *(const short8*)&Vs[cur][rb + (((4+l4) ^ swz7) * 8)];
        oacc[y][nb] = __builtin_amdgcn_mfma_f32_16x16x32_bf16(pa0, v0, oacc[y][nb], 0, 0, 0);
        oacc[y][nb] = __builtin_amdgcn_mfma_f32_16x16x32_bf16(pa1, v1, oacc[y][nb], 0, 0, 0);
      }
      __builtin_amdgcn_s_setprio(0);
    }

    __syncthreads();                           // drains vmcnt (nxt staged) + joins
  }

  #pragma unroll
  for (int y = 0; y < 2; ++y)
    #pragma unroll
    for (int j = 0; j < 4; ++j) {
      float lj = __shfl(lrun[y], l4*4 + j);
      float inv = 1.0f / lj;
      int row = q0 + y*64 + wid*16 + l4*4 + j;
      #pragma unroll
      for (int nb = 0; nb < 4; ++nb) {
        int dim = nb*16 + l15;
        ao[((bidx*S_ + row)*H_ + h)*DK_ + dim] = f2b(oacc[y][nb][j] * inv);
      }
    }
}

// ---------------- kernel 4: output projection (C = A * Wo^T), fp32 out -----------------
__global__ __launch_bounds__(256, 2) void gemm_out_kernel(
    const unsigned short* __restrict__ ao,
    const unsigned short* __restrict__ wob,
    float* __restrict__ out)
{
  __shared__ unsigned short As[2][128 * 64];
  __shared__ unsigned short Bs[2][128 * 64];
  const int tid = threadIdx.x, lane = tid & 63, wid = tid >> 6;
  const int wm = wid >> 1, wn = wid & 1;
  const int m0 = blockIdx.x * 128, n0 = blockIdx.y * 128;
  const int l15 = lane & 15, l4 = lane >> 4;
  const int swz7 = l15 & 7;

  int srow[4], sgcc[4], slds[4];
  #pragma unroll
  for (int j = 0; j < 4; ++j) {
    int c = tid + j * 256;
    srow[j] = c >> 3;
    int cc  = c & 7;
    sgcc[j] = cc ^ (srow[j] & 7);
    slds[j] = (wid * 64 + j * 256) * 8;
  }

  f32x4 acc[4][4] = {};

  #pragma unroll
  for (int j = 0; j < 4; ++j) {
    GLOAD16(ao  + (m0 + srow[j]) * D_ + sgcc[j] * 8, &As[0][slds[j]]);
    GLOAD16(wob + (n0 + srow[j]) * D_ + sgcc[j] * 8, &Bs[0][slds[j]]);
  }
  __syncthreads();

  for (int t = 0; t < 16; ++t) {
    const int cur = t & 1, nxt = cur ^ 1;
    if (t < 15) {
      const int kcol = (t + 1) * 64;
      #pragma unroll
      for (int j = 0; j < 4; ++j) {
        GLOAD16(ao  + (m0 + srow[j]) * D_ + kcol + sgcc[j] * 8, &As[nxt][slds[j]]);
        GLOAD16(wob + (n0 + srow[j]) * D_ + kcol + sgcc[j] * 8, &Bs[nxt][slds[j]]);
      }
    }
    const unsigned short* Ab = &As[cur][0];
    const unsigned short* Bb = &Bs[cur][0];
    #pragma unroll
    for (int ks = 0; ks < 2; ++ks) {
      const int cc = (ks * 4 + l4) ^ swz7;
      short8 af[4], bfr[4];
      #pragma unroll
      for (int mi = 0; mi < 4; ++mi) af[mi]  = *(const short8*)&Ab[(wm*64 + mi*16 + l15)*64 + cc*8];
      #pragma unroll
      for (int ni = 0; ni < 4; ++ni) bfr[ni] = *(const short8*)&Bb[(wn*64 + ni*16 + l15)*64 + cc*8];
      __builtin_amdgcn_s_setprio(1);
      #pragma unroll
      for (int mi = 0; mi < 4; ++mi)
        #pragma unroll
        for (int ni = 0; ni < 4; ++ni)
          acc[mi][ni] = __builtin_amdgcn_mfma_f32_16x16x32_bf16(af[mi], bfr[ni], acc[mi][ni], 0, 0, 0);
      __builtin_amdgcn_s_setprio(0);
    }
    __syncthreads();
  }

  #pragma unroll
  for (int mi = 0; mi < 4; ++mi)
    #pragma unroll
    for (int ni = 0; ni < 4; ++ni)
      #pragma unroll
      for (int j = 0; j < 4; ++j) {
        int row = m0 + wm*64 + mi*16 + l4*4 + j;
        int col = n0 + wn*64 + ni*16 + l15;
        out[row * D_ + col] = acc[mi][ni][j];
      }
}

// ---------------- launcher ----------------
extern "C" void kernel_launch(void* const* d_in, const int* in_sizes, int n_in,
                              void* d_out, int out_size, void* d_ws, size_t ws_size,
                              hipStream_t stream)
{
  const float* x  = (const float*)d_in[0];
  const float* wq = (const float*)d_in[1];
  const float* wk = (const float*)d_in[2];
  const float* wv = (const float*)d_in[3];
  const float* wo = (const float*)d_in[4];
  const float* cs = (const float*)d_in[5];
  const int*  pos = (const int*)d_in[6];
  float* out = (float*)d_out;

  unsigned short* xb = (unsigned short*)d_out;   // d_out as scratch until final GEMM
  unsigned short* wb = xb + M_ * D_;

  unsigned short* qb  = (unsigned short*)d_ws;
  unsigned short* kbf = qb  + M_ * D_;
  unsigned short* vtb = kbf + M_ * D_;
  unsigned short* aob = vtb + M_ * D_;
  unsigned short* wob = qb;                      // dead q region after attn

  conv_kernel<<<dim3(2048), dim3(256), 0, stream>>>(x, wq, wk, wv, xb, wb);
  gemm_qkv_kernel<<<dim3(64, 24), dim3(256), 0, stream>>>(xb, wb, cs, pos, qb, kbf, vtb);
  attn_kernel<<<dim3(1024), dim3(256), 0, stream>>>(qb, kbf, vtb, aob);
  conv_wo_kernel<<<dim3(1024), dim3(256), 0, stream>>>(wo, wob);
  gemm_out_kernel<<<dim3(64, 8), dim3(256), 0, stream>>>(aob, wob, out);

  (void)in_sizes; (void)n_in; (void)out_size; (void)ws_size;
}